// Round 13
// baseline (173.524 us; speedup 1.0000x reference)
//
#include <hip/hip_runtime.h>

typedef __bf16   bf16x8 __attribute__((ext_vector_type(8)));
typedef float    f32x4  __attribute__((ext_vector_type(4)));
typedef float    f32x2  __attribute__((ext_vector_type(2)));
typedef uint32_t u32x4  __attribute__((ext_vector_type(4)));

constexpr int N_ = 16384;
constexpr int D_ = 16;
constexpr int P_ = 8;
constexpr int H_ = 128;
constexpr int M_ = 50;

// prologue-only pack (round-half-up; matches all passing rounds)
__device__ __forceinline__ uint32_t pk_bf16(float a, float b) {
    uint32_t ua = __builtin_bit_cast(uint32_t, a) + 0x8000u;
    uint32_t ub = __builtin_bit_cast(uint32_t, b) + 0x8000u;
    return __builtin_amdgcn_perm(ub, ua, 0x07060302u);   // low=a, high=b
}
// in-loop pack (RNE; validated R7/R8/R11/R12/R14/R15)
__device__ __forceinline__ uint32_t cvtpk(float a, float b) {
    uint32_t r;
    asm("v_cvt_pk_bf16_f32 %0, %1, %2" : "=v"(r) : "v"(a), "v"(b));
    return r;
}
__device__ __forceinline__ uint32_t cvtpk_relu(float a, float b) {
    return cvtpk(fmaxf(a, 0.0f), fmaxf(b, 0.0f));
}

// volatile 16B LDS reads: cannot be promoted across iterations; compiler
// still inserts correct lgkmcnt (R12-proven, no rule-#18 hazard).
__device__ __forceinline__ bf16x8 lds_ldv8(const void* p) {
    u32x4 v = *(volatile const u32x4*)p;
    return __builtin_bit_cast(bf16x8, v);
}
__device__ __forceinline__ f32x4 lds_ldvf(const void* p) {
    u32x4 v = *(volatile const u32x4*)p;
    return __builtin_bit_cast(f32x4, v);
}

// R16: REGISTER-ADDRESSABILITY experiment at 1 wave/SIMD (occupancy closed:
// 4 independent 2-wave configs failed on spill/LDS-chain/barriers).
// Anomaly attacked: R0/R8 VALUBusy = 1240-1425 cyc/step vs ~350 cyc of
// source VALU. Theory: ~290 unified regs > 256 directly-addressable ->
// ~34+ values in the AGPR half -> v_accvgpr_read/write on every per-step
// touch (~450 moves ~= 900 cyc = the missing VALU). Fix: total regs < 256.
//  - w1/w3/b2 -> LDS; volatile reloads placed AFTER last use (cover 500+
//    cyc of following MFMAs — NOT the R12 1-ct-lookahead mistake).
//  - b2 C-in: 4-slot ring, distance-2 prefetch, phase-consistent across
//    iterations ((ct+2)&7 -> slot (ct+2)&3; at ct=6/7 it naturally loads
//    next iteration's ct0/ct1). All indices static after unroll.
//  - L3 interleaved pair-by-pair into L2 (same chain order -> bit-identical;
//    cuts h2b liveness 16->4 regs).
// Ledger: w2f 128 + w1buf 32 + w3buf 16 + cb 16 + b3r 4 + x/e/yw/misc ~15
// + transients ~36 ~= 247 peak < 256.
// GATES: WRITE_SIZE ~1.1MB & VGPR ~240-250; then VALUBusy 46->~27% and dur
// 56->36-45us confirms; VALU flat at ~245 VGPR -> declare roofline next.
__global__ __launch_bounds__(64, 1)
void sde_fused(const float* __restrict__ X0,
               const float* __restrict__ V0,
               const float* __restrict__ Yobs,
               const float* __restrict__ noise,
               const float* __restrict__ W1, const float* __restrict__ b1,
               const float* __restrict__ W2, const float* __restrict__ b2,
               const float* __restrict__ W3, const float* __restrict__ b3,
               float* __restrict__ out)
{
    const int lane = threadIdx.x;
    const int n    = lane & 15;
    const int q    = lane >> 4;
    const int gr   = blockIdx.x * 16 + n;

    const float dt   = 0.02f;
    const float sqdt = 0.1414213562373095f;

    __shared__ bf16x8 w1s[8][64];   // 8 KB
    __shared__ bf16x8 w3s[4][64];   // 4 KB
    __shared__ float  b2s[H_];      // 512 B

    // ---- stage w1/w3/b2 fragments to LDS (transient registers only) ----
#pragma unroll
    for (int ct = 0; ct < 8; ++ct) {
        u32x4 u;
        u[0] = pk_bf16(W1[(1 + q * 4 + 0) * H_ + ct * 16 + n],
                       W1[(1 + q * 4 + 1) * H_ + ct * 16 + n]);
        u[1] = pk_bf16(W1[(1 + q * 4 + 2) * H_ + ct * 16 + n],
                       W1[(1 + q * 4 + 3) * H_ + ct * 16 + n]);
        u[2] = pk_bf16(W1[(17 + q * 2 + 0) * H_ + ct * 16 + n],
                       W1[(17 + q * 2 + 1) * H_ + ct * 16 + n]);
        u[3] = (q == 0) ? pk_bf16(b1[ct * 16 + n], W1[ct * 16 + n]) : 0u;
        w1s[ct][lane] = __builtin_bit_cast(bf16x8, u);
    }
#pragma unroll
    for (int kt = 0; kt < 4; ++kt) {
        u32x4 u;
#pragma unroll
        for (int w = 0; w < 4; ++w) {
            int h0 = (kt * 2 + (w >> 1)) * 16 + q * 4 + (w & 1) * 2;
            u[w] = pk_bf16(W3[h0 * D_ + n], W3[(h0 + 1) * D_ + n]);
        }
        w3s[kt][lane] = __builtin_bit_cast(bf16x8, u);
    }
    if (lane < 32) *(f32x4*)&b2s[lane * 4] = *(const f32x4*)&b2[lane * 4];

    // ---- W2: register-resident (128 regs, 32 uses/step) ----
    bf16x8 w2f[8][4];
#pragma unroll
    for (int ct = 0; ct < 8; ++ct) {
#pragma unroll
        for (int kt = 0; kt < 4; ++kt) {
            u32x4 u;
#pragma unroll
            for (int w = 0; w < 4; ++w) {
                int h0 = (kt * 2 + (w >> 1)) * 16 + q * 4 + (w & 1) * 2;
                u[w] = pk_bf16(W2[h0 * H_ + ct * 16 + n],
                               W2[(h0 + 1) * H_ + ct * 16 + n]);
            }
            w2f[ct][kt] = __builtin_bit_cast(bf16x8, u);
        }
        __builtin_amdgcn_sched_barrier(0);   // cap prologue register spike
    }
    f32x4 b3r = *(const f32x4*)&b3[q * 4];

    __syncthreads();   // LDS staged (single wave; ordering safety)

    // ---- state ----
    f32x4 x = *(const f32x4*)&X0[gr * D_ + q * 4];
    f32x2 y2 = *(const f32x2*)&Yobs[gr * P_ + q * 2];
    const uint32_t yw = pk_bf16(y2[0], y2[1]);
    const float* npb = noise + (size_t)gr * D_ + q * 4;

    // ---- initial buffer fills ----
    bf16x8 w1buf[8];
#pragma unroll
    for (int k = 0; k < 8; ++k) w1buf[k] = lds_ldv8(&w1s[k][lane]);
    bf16x8 w3buf[4];
#pragma unroll
    for (int k = 0; k < 4; ++k) w3buf[k] = lds_ldv8(&w3s[k][lane]);
    f32x4 cb[4];
    cb[0] = lds_ldvf(&b2s[0 * 16 + q * 4]);
    cb[1] = lds_ldvf(&b2s[1 * 16 + q * 4]);

    float t = 0.0f;
    float vacc = 0.0f;

#pragma unroll 1
    for (int m = 0; m < M_; ++m) {
        // this step's noise: loaded at top, used at the end (full-step cover)
        f32x4 e = *(const f32x4*)(npb + (size_t)m * N_ * D_);

        // ---- layer 1 B fragment: [X(4) | Y(2) | one | t] ----
        u32x4 au;
        au[0] = cvtpk(x[0], x[1]);
        au[1] = cvtpk(x[2], x[3]);
        au[2] = yw;
        au[3] = (q == 0) ? cvtpk(1.0f, t) : 0u;
        bf16x8 a0 = __builtin_bit_cast(bf16x8, au);

        // ---- layer 1: pairs; reload each w1 slot right after its use
        //      (next use = next iteration, cover = L2+L3 ~600 cyc) ----
        bf16x8 h1b[4];
#pragma unroll
        for (int kt = 0; kt < 4; ++kt) {
            f32x4 ha = __builtin_amdgcn_mfma_f32_16x16x32_bf16(
                w1buf[2 * kt], a0, (f32x4){0.f, 0.f, 0.f, 0.f}, 0, 0, 0);
            f32x4 hb = __builtin_amdgcn_mfma_f32_16x16x32_bf16(
                w1buf[2 * kt + 1], a0, (f32x4){0.f, 0.f, 0.f, 0.f}, 0, 0, 0);
            w1buf[2 * kt]     = lds_ldv8(&w1s[2 * kt][lane]);
            w1buf[2 * kt + 1] = lds_ldv8(&w1s[2 * kt + 1][lane]);
            u32x4 u;
            u[0] = cvtpk_relu(ha[0], ha[1]);
            u[1] = cvtpk_relu(ha[2], ha[3]);
            u[2] = cvtpk_relu(hb[0], hb[1]);
            u[3] = cvtpk_relu(hb[2], hb[3]);
            h1b[kt] = __builtin_bit_cast(bf16x8, u);
        }

        // ---- layer 2 (ct ascending, R0 chain order) with L3 interleaved
        //      pair-by-pair; b2 C-in via 4-slot distance-2 ring ----
        f32x4 za, zb, hprev;
#pragma unroll
        for (int ct = 0; ct < 8; ++ct) {
            cb[(ct + 2) & 3] = lds_ldvf(&b2s[((ct + 2) & 7) * 16 + q * 4]);
            f32x4 c = cb[ct & 3];
#pragma unroll
            for (int kt = 0; kt < 4; ++kt)
                c = __builtin_amdgcn_mfma_f32_16x16x32_bf16(
                    w2f[ct][kt], h1b[kt], c, 0, 0, 0);
            if ((ct & 1) == 0) {
                hprev = c;
            } else {
                u32x4 u;
                u[0] = cvtpk_relu(hprev[0], hprev[1]);
                u[1] = cvtpk_relu(hprev[2], hprev[3]);
                u[2] = cvtpk_relu(c[0], c[1]);
                u[3] = cvtpk_relu(c[2], c[3]);
                bf16x8 h2b = __builtin_bit_cast(bf16x8, u);
                const int j = ct >> 1;
                if (j == 0) {
                    za = __builtin_amdgcn_mfma_f32_16x16x32_bf16(w3buf[0], h2b, b3r, 0, 0, 0);
                    w3buf[0] = lds_ldv8(&w3s[0][lane]);
                } else if (j == 1) {
                    za = __builtin_amdgcn_mfma_f32_16x16x32_bf16(w3buf[1], h2b, za, 0, 0, 0);
                    w3buf[1] = lds_ldv8(&w3s[1][lane]);
                } else if (j == 2) {
                    zb = __builtin_amdgcn_mfma_f32_16x16x32_bf16(
                        w3buf[2], h2b, (f32x4){0.f, 0.f, 0.f, 0.f}, 0, 0, 0);
                    w3buf[2] = lds_ldv8(&w3s[2][lane]);
                } else {
                    zb = __builtin_amdgcn_mfma_f32_16x16x32_bf16(w3buf[3], h2b, zb, 0, 0, 0);
                    w3buf[3] = lds_ldv8(&w3s[3][lane]);
                }
            }
        }

        // ---- V partial + X update ----
#pragma unroll
        for (int r = 0; r < 4; ++r) {
            float z  = za[r] + zb[r];
            float wn = sqdt * e[r];
            vacc = fmaf(z, wn, fmaf(0.01f * z, z, vacc));   // z*wn + dt/2*z^2
            x[r] = fmaf(x[r], 0.98f, wn);                   // (1-dt)*x + wn
        }

        t += dt;
    }

    // ---- final V reduction across the 4 q-groups ----
    float part = vacc;
    part += __shfl_xor(part, 16);
    part += __shfl_xor(part, 32);
    float v = V0[gr] + part;

    *(f32x4*)&out[gr * D_ + q * 4] = x;
    if (q == 0) out[N_ * D_ + gr] = v;
}

extern "C" void kernel_launch(void* const* d_in, const int* in_sizes, int n_in,
                              void* d_out, int out_size, void* d_ws, size_t ws_size,
                              hipStream_t stream)
{
    const float* X0 = (const float*)d_in[0];
    const float* V0 = (const float*)d_in[1];
    const float* Y  = (const float*)d_in[2];
    const float* nz = (const float*)d_in[3];
    const float* W1 = (const float*)d_in[4];
    const float* b1 = (const float*)d_in[5];
    const float* W2 = (const float*)d_in[6];
    const float* b2 = (const float*)d_in[7];
    const float* W3 = (const float*)d_in[8];
    const float* b3 = (const float*)d_in[9];
    float* out = (float*)d_out;

    sde_fused<<<N_ / 16, 64, 0, stream>>>(X0, V0, Y, nz, W1, b1, W2, b2, W3, b3, out);
}